// Round 1
// baseline (45.523 us; speedup 1.0000x reference)
//
#include <hip/hip_runtime.h>

#define B_ 4
#define N_ 64
#define H_ 512
#define W_ 512
#define MH 28
#define MW 28

// params layout per box (8 floats): ymin, ymax, xmin, xmax, sy, sx, valid, pad
__global__ __launch_bounds__(256) void params_kernel(const float* __restrict__ det,
                                                     float* __restrict__ p) {
    __shared__ float red[256];
    int t = threadIdx.x;                 // t indexes the B*N = 256 boxes
    float sc = det[t * 6 + 5];
    red[t] = sc;
    __syncthreads();
    for (int s = 128; s > 0; s >>= 1) {
        if (t < s) red[t] = fmaxf(red[t], red[t + s]);
        __syncthreads();
    }
    float thr = (red[0] > 50.0f) ? 50.0f : -100.0f;

    float cx = fmaxf(det[t * 6 + 0], 1.0f);
    float cy = fmaxf(det[t * 6 + 1], 1.0f);
    float w  = fmaxf(det[t * 6 + 2], 1.0f);
    float h  = fmaxf(det[t * 6 + 3], 1.0f);
    int xmin = min(max((int)ceilf(cx - w * 0.5f), 0), W_);
    int xmax = min(max((int)ceilf(cx + w * 0.5f), 0), W_);
    int ymin = min(max((int)ceilf(cy - h * 0.5f), 0), H_);
    int ymax = min(max((int)ceilf(cy + h * 0.5f), 0), H_);
    float out_h = (float)(ymax - ymin);
    float out_w = (float)(xmax - xmin);
    float sy = (out_h > 1.0f) ? (float)(MH - 1) / fmaxf(out_h - 1.0f, 1.0f) : 0.0f;
    float sx = (out_w > 1.0f) ? (float)(MW - 1) / fmaxf(out_w - 1.0f, 1.0f) : 0.0f;

    float* o = p + t * 8;
    o[0] = (float)ymin;
    o[1] = (float)ymax;
    o[2] = (float)xmin;
    o[3] = (float)xmax;
    o[4] = sy;
    o[5] = sx;
    o[6] = (sc >= thr) ? 1.0f : 0.0f;
    o[7] = 0.0f;
}

// One block per (bn, 2-row chunk). 256 threads: 128 threads per row, 4 px/thread.
__global__ __launch_bounds__(256) void paste_kernel(const float* __restrict__ ins,
                                                    const float* __restrict__ p,
                                                    float* __restrict__ out) {
    int bid   = blockIdx.x;
    int bn    = bid >> 8;        // H_/2 = 256 chunks per box
    int chunk = bid & 255;
    int t     = threadIdx.x;
    int y     = chunk * 2 + (t >> 7);
    int x0    = (t & 127) << 2;

    const float* q = p + bn * 8;
    float yminf = q[0], ymaxf = q[1], xminf = q[2], xmaxf = q[3];
    float sy = q[4], sx = q[5], valid = q[6];

    float4 r = make_float4(0.f, 0.f, 0.f, 0.f);
    float yf = (float)y;
    if (valid != 0.0f && yf >= yminf && yf < ymaxf) {
        float src_y = fminf(fmaxf((yf - yminf) * sy, 0.0f), (float)(MH - 1));
        float y0f = floorf(src_y);
        int   y0  = (int)y0f;
        int   y1  = min(y0 + 1, MH - 1);
        float wy  = src_y - y0f;
        const float* m  = ins + (size_t)bn * (MH * MW);
        const float* m0 = m + y0 * MW;
        const float* m1 = m + y1 * MW;
        float vals[4];
#pragma unroll
        for (int j = 0; j < 4; ++j) {
            float xf = (float)(x0 + j);
            float v  = 0.0f;
            if (xf >= xminf && xf < xmaxf) {
                float src_x = fminf(fmaxf((xf - xminf) * sx, 0.0f), (float)(MW - 1));
                float x0f = floorf(src_x);
                int   xi0 = (int)x0f;
                int   xi1 = min(xi0 + 1, MW - 1);
                float wx  = src_x - x0f;
                float a0 = m0[xi0], b0 = m1[xi0];
                float a1 = m0[xi1], b1 = m1[xi1];
                float r0 = a0 * (1.0f - wy) + b0 * wy;   // row-first, matches ref order
                float r1 = a1 * (1.0f - wy) + b1 * wy;
                v = r0 * (1.0f - wx) + r1 * wx;
            }
            vals[j] = v;
        }
        r = make_float4(vals[0], vals[1], vals[2], vals[3]);
    }
    float4* optr = (float4*)(out + ((size_t)bn * H_ + y) * W_ + x0);
    *optr = r;
}

extern "C" void kernel_launch(void* const* d_in, const int* in_sizes, int n_in,
                              void* d_out, int out_size, void* d_ws, size_t ws_size,
                              hipStream_t stream) {
    const float* det = (const float*)d_in[1];   // [B,N,6]
    const float* ins = (const float*)d_in[2];   // [B,N,MH,MW]
    float* out = (float*)d_out;                 // [B,N,H,W]
    float* params = (float*)d_ws;               // 256 * 8 floats

    params_kernel<<<1, 256, 0, stream>>>(det, params);
    paste_kernel<<<B_ * N_ * (H_ / 2), 256, 0, stream>>>(ins, params, out);
}